// Round 4
// baseline (182.583 us; speedup 1.0000x reference)
//
#include <hip/hip_runtime.h>

// DCN-v2 low-rank mixture, L=3 E=4 D=512 R=64 B=16384.
// gate = softmax over size-1 axis == 1  -> G unused.
// xl' = x0 * (sum_e U_e tanh(C_e tanh(V_e^T xl)) + 4*bias) + xl, rows independent.
// Fused kernel, bf16 MFMA (16x16x32), fp32 xl state in VGPRs.
// R4: 512-thread blocks (8 waves), 16 waves/CU, separate cvbuf (3 barriers/layer),
//     single global read of x (xl_b built from xlr fragments).

#define NL 3
#define NE 4
#define DD 512
#define RR 64
#define ROWS 32    // rows per block; grid = 16384/32 = 512 blocks
#define THREADS 512

typedef __attribute__((ext_vector_type(8))) short bf16x8;   // 8 bf16 = 4 VGPR
typedef __attribute__((ext_vector_type(4))) float f32x4;

#define MFMA(a, b, c) __builtin_amdgcn_mfma_f32_16x16x32_bf16((a), (b), (c), 0, 0, 0)

__device__ __forceinline__ short bf16rn(float f) {   // round-to-nearest-even f32->bf16
    unsigned u = __builtin_bit_cast(unsigned, f);
    u += 0x7fffu + ((u >> 16) & 1u);
    return (short)(u >> 16);
}

__device__ __forceinline__ float ftanh(float x) {
    float t = __builtin_amdgcn_exp2f(x * 2.8853900817779268f);
    return 1.0f - 2.0f * __builtin_amdgcn_rcpf(t + 1.0f);
}

// ---- prep: cast weights to bf16, transpose V and C for contiguous-k B-fragments ----
// Vb[(l,e)][r][d] = V[(l,e)][d][r];  Ub = U ([e][d][s], k=s contiguous);
// Ct[(l,e)][s][r] = C[(l,e)][r][s]
__global__ void prep_kernel(const float* __restrict__ U, const float* __restrict__ V,
                            const float* __restrict__ C,
                            short* __restrict__ Vb, short* __restrict__ Ub,
                            short* __restrict__ Ct)
{
    int tid  = blockIdx.x * 256 + threadIdx.x;
    int nthr = gridDim.x * 256;
    for (int i = tid; i < NL * NE * DD * RR; i += nthr) Ub[i] = bf16rn(U[i]);
    for (int i = tid; i < NL * NE * DD * RR; i += nthr) {
        int le = i >> 15;
        int rem = i & 32767;
        int r = rem >> 9;
        int d = rem & 511;
        Vb[i] = bf16rn(V[(le << 15) + (d << 6) + r]);
    }
    for (int i = tid; i < NL * NE * RR * RR; i += nthr) {
        int le = i >> 12;
        int rem = i & 4095;
        int s = rem >> 6;
        int r = rem & 63;
        Ct[i] = bf16rn(C[(le << 12) + (r << 6) + s]);
    }
}

// XOR swizzle: breaks the 16-way bank conflict of row-major bf16 tiles on ds_read_b128
#define XLB_ADDR(row, colbyte) (((row) * (DD * 2)) + ((colbyte) ^ (((row) & 7) << 4)))
#define VB_ADDR(row, colbyte)  (((row) * (NE * RR * 2)) + ((colbyte) ^ (((row) & 7) << 4)))

__global__ __launch_bounds__(THREADS, 4) void dcn_main(
    const float* __restrict__ x,
    const float* __restrict__ bias,
    const short* __restrict__ Vb,
    const short* __restrict__ Ub,
    const short* __restrict__ Ct,
    float* __restrict__ out)
{
    __shared__ char xl_b[ROWS * DD * 2];        // 32 KiB bf16 xl tile (swizzled)
    __shared__ char vbuf[ROWS * NE * RR * 2];   // 16 KiB bf16 v tile (swizzled)
    __shared__ char cvbuf[ROWS * NE * RR * 2];  // 16 KiB bf16 cv tile (swizzled)

    const int t   = threadIdx.x;
    const int w   = t >> 6;          // wave 0..7
    const int ln  = t & 63;
    const int l15 = ln & 15;
    const int kg  = ln >> 4;         // k-group 0..3
    const int row_base = blockIdx.x * ROWS;

    // ---- preamble: single global read of x -> xlr (fp32), x0p (bf16x2), xl_b (bf16 LDS) ----
    float    xlr[2][4][4];   // fp32 xl state, GEMM3 D-frag layout (wave owns 64 cols)
    unsigned x0p[2][4][2];   // x0 packed bf16x2
    #pragma unroll
    for (int mt = 0; mt < 2; ++mt)
      #pragma unroll
      for (int nt = 0; nt < 4; ++nt) {
          int col = w * 64 + nt * 16 + l15;
          int row0 = mt * 16 + kg * 4;
          const float* xp = x + (size_t)(row_base + row0) * DD + col;
          float v0 = xp[0], v1 = xp[DD], v2 = xp[2 * DD], v3 = xp[3 * DD];
          xlr[mt][nt][0] = v0; xlr[mt][nt][1] = v1; xlr[mt][nt][2] = v2; xlr[mt][nt][3] = v3;
          short b0 = bf16rn(v0), b1 = bf16rn(v1), b2 = bf16rn(v2), b3 = bf16rn(v3);
          x0p[mt][nt][0] = (unsigned)(unsigned short)b0 | ((unsigned)(unsigned short)b1 << 16);
          x0p[mt][nt][1] = (unsigned)(unsigned short)b2 | ((unsigned)(unsigned short)b3 << 16);
          *(short*)(xl_b + XLB_ADDR(row0 + 0, col * 2)) = b0;
          *(short*)(xl_b + XLB_ADDR(row0 + 1, col * 2)) = b1;
          *(short*)(xl_b + XLB_ADDR(row0 + 2, col * 2)) = b2;
          *(short*)(xl_b + XLB_ADDR(row0 + 3, col * 2)) = b3;
      }
    __syncthreads();

    const int e2 = w >> 1;           // GEMM2 expert for this wave
    const int h2 = w & 1;            // GEMM2 column-half within expert

    for (int layer = 0; layer < NL; ++layer) {
        const short* Vl = Vb + layer * (NE * DD * RR);
        const short* Ul = Ub + layer * (NE * DD * RR);
        const short* Cl = Ct + layer * (NE * RR * RR);
        const float* bl = bias + layer * DD;

        // ---- GEMM1: v = tanh(xl @ V); wave owns v-cols [w*32, w*32+32) ----
        f32x4 acc1[2][2];
        #pragma unroll
        for (int mt = 0; mt < 2; ++mt)
          #pragma unroll
          for (int nt = 0; nt < 2; ++nt) { f32x4 z = {0.f, 0.f, 0.f, 0.f}; acc1[mt][nt] = z; }

        #pragma unroll 4
        for (int ks = 0; ks < 16; ++ks) {
            const int d0 = ks * 32 + kg * 8;
            bf16x8 a0 = *(const bf16x8*)(xl_b + XLB_ADDR(l15,      d0 * 2));
            bf16x8 a1 = *(const bf16x8*)(xl_b + XLB_ADDR(l15 + 16, d0 * 2));
            #pragma unroll
            for (int nt = 0; nt < 2; ++nt) {
                bf16x8 b = *(const bf16x8*)(Vl + (size_t)(w * 32 + nt * 16 + l15) * DD + d0);
                acc1[0][nt] = MFMA(a0, b, acc1[0][nt]);
                acc1[1][nt] = MFMA(a1, b, acc1[1][nt]);
            }
        }
        #pragma unroll
        for (int mt = 0; mt < 2; ++mt)
          #pragma unroll
          for (int nt = 0; nt < 2; ++nt)
            #pragma unroll
            for (int r = 0; r < 4; ++r) {
                int row = mt * 16 + kg * 4 + r;
                int col = w * 32 + nt * 16 + l15;
                *(short*)(vbuf + VB_ADDR(row, col * 2)) = bf16rn(ftanh(acc1[mt][nt][r]));
            }
        __syncthreads();

        // ---- GEMM2: cv = tanh(v @ C_e); wave pair (2e,2e+1) owns expert e ----
        f32x4 acc2[2][2];
        #pragma unroll
        for (int mt = 0; mt < 2; ++mt)
          #pragma unroll
          for (int nt = 0; nt < 2; ++nt) { f32x4 z = {0.f, 0.f, 0.f, 0.f}; acc2[mt][nt] = z; }

        #pragma unroll
        for (int kc = 0; kc < 2; ++kc) {
            const int r0 = kc * 32 + kg * 8;
            const int vcol = e2 * 64 + r0;
            bf16x8 a0 = *(const bf16x8*)(vbuf + VB_ADDR(l15,      vcol * 2));
            bf16x8 a1 = *(const bf16x8*)(vbuf + VB_ADDR(l15 + 16, vcol * 2));
            #pragma unroll
            for (int nt = 0; nt < 2; ++nt) {
                int outc = h2 * 32 + nt * 16 + l15;
                bf16x8 b = *(const bf16x8*)(Cl + (size_t)e2 * (RR * RR) + outc * RR + r0);
                acc2[0][nt] = MFMA(a0, b, acc2[0][nt]);
                acc2[1][nt] = MFMA(a1, b, acc2[1][nt]);
            }
        }
        #pragma unroll
        for (int mt = 0; mt < 2; ++mt)
          #pragma unroll
          for (int nt = 0; nt < 2; ++nt)
            #pragma unroll
            for (int r = 0; r < 4; ++r) {
                int row = mt * 16 + kg * 4 + r;
                int col = e2 * 64 + h2 * 32 + nt * 16 + l15;
                *(short*)(cvbuf + VB_ADDR(row, col * 2)) = bf16rn(ftanh(acc2[mt][nt][r]));
            }
        __syncthreads();

        // ---- GEMM3: ucv = cv @ W, W[(e,s)][d] = U[e][d][s]; wave owns d-cols [w*64, w*64+64) ----
        f32x4 acc3[2][4];
        #pragma unroll
        for (int mt = 0; mt < 2; ++mt)
          #pragma unroll
          for (int nt = 0; nt < 4; ++nt) { f32x4 z = {0.f, 0.f, 0.f, 0.f}; acc3[mt][nt] = z; }

        #pragma unroll 4
        for (int ks = 0; ks < 8; ++ks) {
            const int k0 = ks * 32 + kg * 8;
            bf16x8 a0 = *(const bf16x8*)(cvbuf + VB_ADDR(l15,      k0 * 2));
            bf16x8 a1 = *(const bf16x8*)(cvbuf + VB_ADDR(l15 + 16, k0 * 2));
            const int e  = ks >> 1;        // K=32 block stays inside one expert
            const int s0 = k0 & 63;
            #pragma unroll
            for (int nt = 0; nt < 4; ++nt) {
                int dcol = w * 64 + nt * 16 + l15;
                bf16x8 b = *(const bf16x8*)(Ul + (size_t)e * (DD * RR) + dcol * RR + s0);
                acc3[0][nt] = MFMA(a0, b, acc3[0][nt]);
                acc3[1][nt] = MFMA(a1, b, acc3[1][nt]);
            }
        }

        // ---- epilogue: xl' = x0*(ucv + 4*bias) + xl  (fp32 state in regs) ----
        const bool lastL = (layer == NL - 1);
        #pragma unroll
        for (int nt = 0; nt < 4; ++nt) {
            int col = w * 64 + nt * 16 + l15;
            float bv = 4.0f * bl[col];
            #pragma unroll
            for (int mt = 0; mt < 2; ++mt) {
                unsigned p0 = x0p[mt][nt][0], p1 = x0p[mt][nt][1];
                float x0v0 = __builtin_bit_cast(float, p0 << 16);
                float x0v1 = __builtin_bit_cast(float, p0 & 0xffff0000u);
                float x0v2 = __builtin_bit_cast(float, p1 << 16);
                float x0v3 = __builtin_bit_cast(float, p1 & 0xffff0000u);
                xlr[mt][nt][0] = x0v0 * (acc3[mt][nt][0] + bv) + xlr[mt][nt][0];
                xlr[mt][nt][1] = x0v1 * (acc3[mt][nt][1] + bv) + xlr[mt][nt][1];
                xlr[mt][nt][2] = x0v2 * (acc3[mt][nt][2] + bv) + xlr[mt][nt][2];
                xlr[mt][nt][3] = x0v3 * (acc3[mt][nt][3] + bv) + xlr[mt][nt][3];
            }
        }
        if (lastL) {
            #pragma unroll
            for (int mt = 0; mt < 2; ++mt)
              #pragma unroll
              for (int nt = 0; nt < 4; ++nt) {
                  int col = w * 64 + nt * 16 + l15;
                  float* op = out + (size_t)(row_base + mt * 16 + kg * 4) * DD + col;
                  op[0]      = xlr[mt][nt][0];
                  op[DD]     = xlr[mt][nt][1];
                  op[2 * DD] = xlr[mt][nt][2];
                  op[3 * DD] = xlr[mt][nt][3];
              }
        } else {
            // refresh bf16 xl tile for next layer's GEMM1 A-fragments
            #pragma unroll
            for (int mt = 0; mt < 2; ++mt)
              #pragma unroll
              for (int nt = 0; nt < 4; ++nt) {
                  int col = w * 64 + nt * 16 + l15;
                  #pragma unroll
                  for (int r = 0; r < 4; ++r) {
                      int row = mt * 16 + kg * 4 + r;
                      *(short*)(xl_b + XLB_ADDR(row, col * 2)) = bf16rn(xlr[mt][nt][r]);
                  }
              }
            __syncthreads();
        }
    }
}

extern "C" void kernel_launch(void* const* d_in, const int* in_sizes, int n_in,
                              void* d_out, int out_size, void* d_ws, size_t ws_size,
                              hipStream_t stream) {
    const float* x    = (const float*)d_in[0];
    const float* U    = (const float*)d_in[1];
    const float* V    = (const float*)d_in[2];
    const float* C    = (const float*)d_in[3];
    // d_in[4] = G : unused (gate == 1 exactly)
    const float* bias = (const float*)d_in[5];
    float* out = (float*)d_out;

    short* Vb = (short*)d_ws;                 // 786432 B
    short* Ub = Vb + NL * NE * DD * RR;       // 786432 B
    short* Ct = Ub + NL * NE * DD * RR;       // 98304 B  (total ~1.6 MiB)

    prep_kernel<<<dim3(256), dim3(256), 0, stream>>>(U, V, C, Vb, Ub, Ct);
    dcn_main<<<dim3(16384 / ROWS), dim3(THREADS), 0, stream>>>(x, bias, Vb, Ub, Ct, out);
}

// Round 5
// 168.936 us; speedup vs baseline: 1.0808x; 1.0808x over previous
//
#include <hip/hip_runtime.h>

// DCN-v2 low-rank mixture, L=3 E=4 D=512 R=64 B=16384.
// gate = softmax over size-1 axis == 1  -> G unused.
// xl' = x0 * (sum_e U_e tanh(C_e tanh(V_e^T xl)) + 4*bias) + xl, rows independent.
// R5: fragment-contiguous weight layouts (1KB coalesced wave-loads for every
//     MFMA B-fragment), ROWS=16 / 256 thr / grid 1024 -> 16 waves/CU spill-free,
//     2 barriers per layer (GEMM1->GEMM2 is wave-local).

#define NL 3
#define NE 4
#define DD 512
#define RR 64
#define ROWS 16    // rows per block; grid = 16384/16 = 1024 blocks
#define THREADS 256

typedef __attribute__((ext_vector_type(8))) short bf16x8;   // 8 bf16 = 4 VGPR
typedef __attribute__((ext_vector_type(4))) float f32x4;

#define MFMA(a, b, c) __builtin_amdgcn_mfma_f32_16x16x32_bf16((a), (b), (c), 0, 0, 0)

__device__ __forceinline__ short bf16rn(float f) {   // round-to-nearest-even f32->bf16
    unsigned u = __builtin_bit_cast(unsigned, f);
    u += 0x7fffu + ((u >> 16) & 1u);
    return (short)(u >> 16);
}

__device__ __forceinline__ float ftanh(float x) {
    float t = __builtin_amdgcn_exp2f(x * 2.8853900817779268f);
    return 1.0f - 2.0f * __builtin_amdgcn_rcpf(t + 1.0f);
}

// ---- prep: bf16-cast + permute weights into MFMA-fragment-contiguous order ----
// Fragment element (lane ln, j): col = 16*colblk + (ln&15), k = 32*kstep + (ln>>4)*8 + j.
// Vb2[l][colblk(16)][ks(16)][ln(64)][j(8)]  = V[l][e=colblk>>2][d=32ks+8(ln>>4)+j][r=16(colblk&3)+(ln&15)]
// Ub2[l][dblk(32)][ks(8)][ln][j]            = U[l][e=ks>>1][d=16dblk+(ln&15)][s=32(ks&1)+8(ln>>4)+j]
// Ct2[l][e(4)][oc(4)][kc(2)][ln][j]         = C[l][e][r=32kc+8(ln>>4)+j][s=16oc+(ln&15)]
__global__ void prep_kernel(const float* __restrict__ U, const float* __restrict__ V,
                            const float* __restrict__ C,
                            short* __restrict__ Vb2, short* __restrict__ Ub2,
                            short* __restrict__ Ct2)
{
    int tid  = blockIdx.x * 256 + threadIdx.x;
    int nthr = gridDim.x * 256;
    for (int i = tid; i < NL * 131072; i += nthr) {
        int l = i >> 17; int q = i & 131071;
        int colblk = q >> 13; int rem = q & 8191;
        int ks = rem >> 9; int ln = (rem >> 3) & 63; int j = rem & 7;
        int e = colblk >> 2;
        int r = (colblk & 3) * 16 + (ln & 15);
        int d = ks * 32 + (ln >> 4) * 8 + j;
        Vb2[i] = bf16rn(V[(((size_t)l * NE + e) * DD + d) * RR + r]);
    }
    for (int i = tid; i < NL * 131072; i += nthr) {
        int l = i >> 17; int q = i & 131071;
        int dblk = q >> 12; int rem = q & 4095;
        int ks = rem >> 9; int ln = (rem >> 3) & 63; int j = rem & 7;
        int e = ks >> 1;
        int d = dblk * 16 + (ln & 15);
        int s = (ks & 1) * 32 + (ln >> 4) * 8 + j;
        Ub2[i] = bf16rn(U[(((size_t)l * NE + e) * DD + d) * RR + s]);
    }
    for (int i = tid; i < NL * 16384; i += nthr) {
        int l = i >> 14; int q = i & 16383;
        int e = q >> 12; int rem = q & 4095;
        int oc = rem >> 10; int kc = (rem >> 9) & 1;
        int ln = (rem >> 3) & 63; int j = rem & 7;
        int r = kc * 32 + (ln >> 4) * 8 + j;
        int s = oc * 16 + (ln & 15);
        Ct2[i] = bf16rn(C[(((size_t)l * NE + e) * RR + r) * RR + s]);
    }
}

// XOR swizzle: breaks the bank conflict of row-major bf16 tiles on ds_read_b128
#define XLB_ADDR(row, colbyte) (((row) * (DD * 2)) + ((colbyte) ^ (((row) & 7) << 4)))
#define VB_ADDR(row, colbyte)  (((row) * (NE * RR * 2)) + ((colbyte) ^ (((row) & 7) << 4)))

__global__ __launch_bounds__(THREADS, 4) void dcn_main(
    const float* __restrict__ x,
    const float* __restrict__ bias,
    const short* __restrict__ Vb2,
    const short* __restrict__ Ub2,
    const short* __restrict__ Ct2,
    float* __restrict__ out)
{
    __shared__ char xl_b[ROWS * DD * 2];        // 16 KiB bf16 xl tile (swizzled)
    __shared__ char vbuf[ROWS * NE * RR * 2];   //  8 KiB bf16 v tile (swizzled)
    __shared__ char cvbuf[ROWS * NE * RR * 2];  //  8 KiB bf16 cv tile (swizzled)

    const int t   = threadIdx.x;
    const int w   = t >> 6;          // wave 0..3
    const int ln  = t & 63;
    const int l15 = ln & 15;
    const int kg  = ln >> 4;         // k-group 0..3
    const int row_base = blockIdx.x * ROWS;

    // ---- preamble: single global read of x -> xlr (fp32), x0p (bf16x2), xl_b (bf16 LDS) ----
    float    xlr[8][4];   // fp32 xl state; wave owns d-cols [w*128, w*128+128)
    unsigned x0p[8][2];   // x0 packed bf16x2
    #pragma unroll
    for (int nt = 0; nt < 8; ++nt) {
        int col  = w * 128 + nt * 16 + l15;
        int row0 = kg * 4;
        const float* xp = x + (size_t)(row_base + row0) * DD + col;
        float v0 = xp[0], v1 = xp[DD], v2 = xp[2 * DD], v3 = xp[3 * DD];
        xlr[nt][0] = v0; xlr[nt][1] = v1; xlr[nt][2] = v2; xlr[nt][3] = v3;
        short b0 = bf16rn(v0), b1 = bf16rn(v1), b2 = bf16rn(v2), b3 = bf16rn(v3);
        x0p[nt][0] = (unsigned)(unsigned short)b0 | ((unsigned)(unsigned short)b1 << 16);
        x0p[nt][1] = (unsigned)(unsigned short)b2 | ((unsigned)(unsigned short)b3 << 16);
        *(short*)(xl_b + XLB_ADDR(row0 + 0, col * 2)) = b0;
        *(short*)(xl_b + XLB_ADDR(row0 + 1, col * 2)) = b1;
        *(short*)(xl_b + XLB_ADDR(row0 + 2, col * 2)) = b2;
        *(short*)(xl_b + XLB_ADDR(row0 + 3, col * 2)) = b3;
    }
    __syncthreads();

    for (int layer = 0; layer < NL; ++layer) {
        const short* Vl = Vb2 + layer * 131072;
        const short* Ul = Ub2 + layer * 131072;
        const short* Cl = Ct2 + layer * 16384;
        const float* bl = bias + layer * DD;

        // ---- GEMM1: v = tanh(xl @ V); wave owns v-cols [w*64, w*64+64) ----
        // B-fragment: Vl frag (colblk = w*4+nt, ks), contiguous 1KB per wave-load.
        f32x4 acc1[4];
        #pragma unroll
        for (int nt = 0; nt < 4; ++nt) { f32x4 z = {0.f, 0.f, 0.f, 0.f}; acc1[nt] = z; }

        #pragma unroll 4
        for (int ks = 0; ks < 16; ++ks) {
            const int d0 = ks * 32 + kg * 8;
            bf16x8 a0 = *(const bf16x8*)(xl_b + XLB_ADDR(l15, d0 * 2));
            #pragma unroll
            for (int nt = 0; nt < 4; ++nt) {
                bf16x8 b = *(const bf16x8*)(Vl + (((w * 4 + nt) * 16 + ks) << 9) + ln * 8);
                acc1[nt] = MFMA(a0, b, acc1[nt]);
            }
        }
        // v write is wave-local (wave w produces exactly the cols its GEMM2 reads)
        #pragma unroll
        for (int nt = 0; nt < 4; ++nt)
          #pragma unroll
          for (int r = 0; r < 4; ++r) {
              int row = kg * 4 + r;
              int col = w * 64 + nt * 16 + l15;
              *(short*)(vbuf + VB_ADDR(row, col * 2)) = bf16rn(ftanh(acc1[nt][r]));
          }
        // no __syncthreads: GEMM2 expert w reads only wave-w's vbuf cols (lgkmcnt suffices)

        // ---- GEMM2: cv = tanh(v @ C_e); wave w owns expert e = w entirely ----
        f32x4 acc2[4];
        #pragma unroll
        for (int nt = 0; nt < 4; ++nt) { f32x4 z = {0.f, 0.f, 0.f, 0.f}; acc2[nt] = z; }

        #pragma unroll
        for (int kc = 0; kc < 2; ++kc) {
            const int r0 = kc * 32 + kg * 8;
            bf16x8 a0 = *(const bf16x8*)(vbuf + VB_ADDR(l15, (w * 64 + r0) * 2));
            #pragma unroll
            for (int nt = 0; nt < 4; ++nt) {
                bf16x8 b = *(const bf16x8*)(Cl + (((w * 4 + nt) * 2 + kc) << 9) + ln * 8);
                acc2[nt] = MFMA(a0, b, acc2[nt]);
            }
        }
        #pragma unroll
        for (int nt = 0; nt < 4; ++nt)
          #pragma unroll
          for (int r = 0; r < 4; ++r) {
              int row = kg * 4 + r;
              int col = w * 64 + nt * 16 + l15;
              *(short*)(cvbuf + VB_ADDR(row, col * 2)) = bf16rn(ftanh(acc2[nt][r]));
          }
        __syncthreads();   // GEMM3 reads all experts' cv cols

        // ---- GEMM3: ucv = cv @ W, W[(e,s)][d] = U[e][d][s]; wave owns d-cols [w*128, +128) ----
        f32x4 acc3[8];
        #pragma unroll
        for (int nt = 0; nt < 8; ++nt) { f32x4 z = {0.f, 0.f, 0.f, 0.f}; acc3[nt] = z; }

        #pragma unroll 4
        for (int ks = 0; ks < 8; ++ks) {
            const int k0 = ks * 32 + kg * 8;
            bf16x8 a0 = *(const bf16x8*)(cvbuf + VB_ADDR(l15, k0 * 2));
            #pragma unroll
            for (int nt = 0; nt < 8; ++nt) {
                bf16x8 b = *(const bf16x8*)(Ul + (((w * 8 + nt) * 8 + ks) << 9) + ln * 8);
                acc3[nt] = MFMA(a0, b, acc3[nt]);
            }
        }

        // ---- epilogue: xl' = x0*(ucv + 4*bias) + xl  (fp32 state in regs) ----
        const bool lastL = (layer == NL - 1);
        #pragma unroll
        for (int nt = 0; nt < 8; ++nt) {
            int col = w * 128 + nt * 16 + l15;
            float bv = 4.0f * bl[col];
            unsigned p0 = x0p[nt][0], p1 = x0p[nt][1];
            float x0v0 = __builtin_bit_cast(float, p0 << 16);
            float x0v1 = __builtin_bit_cast(float, p0 & 0xffff0000u);
            float x0v2 = __builtin_bit_cast(float, p1 << 16);
            float x0v3 = __builtin_bit_cast(float, p1 & 0xffff0000u);
            xlr[nt][0] = x0v0 * (acc3[nt][0] + bv) + xlr[nt][0];
            xlr[nt][1] = x0v1 * (acc3[nt][1] + bv) + xlr[nt][1];
            xlr[nt][2] = x0v2 * (acc3[nt][2] + bv) + xlr[nt][2];
            xlr[nt][3] = x0v3 * (acc3[nt][3] + bv) + xlr[nt][3];
        }
        if (lastL) {
            #pragma unroll
            for (int nt = 0; nt < 8; ++nt) {
                int col = w * 128 + nt * 16 + l15;
                float* op = out + (size_t)(row_base + kg * 4) * DD + col;
                op[0]      = xlr[nt][0];
                op[DD]     = xlr[nt][1];
                op[2 * DD] = xlr[nt][2];
                op[3 * DD] = xlr[nt][3];
            }
        } else {
            // refresh bf16 xl tile for next layer's GEMM1 A-fragments
            #pragma unroll
            for (int nt = 0; nt < 8; ++nt) {
                int col = w * 128 + nt * 16 + l15;
                #pragma unroll
                for (int r = 0; r < 4; ++r)
                    *(short*)(xl_b + XLB_ADDR(kg * 4 + r, col * 2)) = bf16rn(xlr[nt][r]);
            }
            __syncthreads();
        }
    }
}

extern "C" void kernel_launch(void* const* d_in, const int* in_sizes, int n_in,
                              void* d_out, int out_size, void* d_ws, size_t ws_size,
                              hipStream_t stream) {
    const float* x    = (const float*)d_in[0];
    const float* U    = (const float*)d_in[1];
    const float* V    = (const float*)d_in[2];
    const float* C    = (const float*)d_in[3];
    // d_in[4] = G : unused (gate == 1 exactly)
    const float* bias = (const float*)d_in[5];
    float* out = (float*)d_out;

    short* Vb2 = (short*)d_ws;                 // 786432 B
    short* Ub2 = Vb2 + NL * 131072;            // 786432 B
    short* Ct2 = Ub2 + NL * 131072;            // 98304 B  (total ~1.6 MiB)

    prep_kernel<<<dim3(256), dim3(256), 0, stream>>>(U, V, C, Vb2, Ub2, Ct2);
    dcn_main<<<dim3(16384 / ROWS), dim3(THREADS), 0, stream>>>(x, bias, Vb2, Ub2, Ct2, out);
}

// Round 6
// 157.837 us; speedup vs baseline: 1.1568x; 1.0703x over previous
//
#include <hip/hip_runtime.h>

// DCN-v2 low-rank mixture, L=3 E=4 D=512 R=64 B=16384.
// gate = softmax over size-1 axis == 1  -> G unused.
// xl' = x0 * (sum_e U_e tanh(C_e tanh(V_e^T xl)) + 4*bias) + xl, rows independent.
// R6: kill the spills. amdgpu_waves_per_eu(4,4) pins the 128-VGPR tier;
//     8 waves x ROWS=32 halves per-wave state (xlr 32 + x0p 16 persistent);
//     GEMM3 split into two nt-halves; depth-2 ping-pong B prefetch;
//     grid=512 halves the L2 weight-stream floor (~23 us).

#define NL 3
#define NE 4
#define DD 512
#define RR 64
#define ROWS 32    // rows per block; grid = 16384/32 = 512 blocks
#define THREADS 512

typedef __attribute__((ext_vector_type(8))) short bf16x8;   // 8 bf16 = 4 VGPR
typedef __attribute__((ext_vector_type(4))) float f32x4;

#define MFMA(a, b, c) __builtin_amdgcn_mfma_f32_16x16x32_bf16((a), (b), (c), 0, 0, 0)

__device__ __forceinline__ short bf16rn(float f) {   // round-to-nearest-even f32->bf16
    unsigned u = __builtin_bit_cast(unsigned, f);
    u += 0x7fffu + ((u >> 16) & 1u);
    return (short)(u >> 16);
}

__device__ __forceinline__ float ftanh(float x) {
    float t = __builtin_amdgcn_exp2f(x * 2.8853900817779268f);
    return 1.0f - 2.0f * __builtin_amdgcn_rcpf(t + 1.0f);
}

// ---- prep: bf16-cast + permute weights into MFMA-fragment-contiguous order ----
// Fragment element (lane ln, j): col = 16*colblk + (ln&15), k = 32*kstep + (ln>>4)*8 + j.
// Vb2[l][colblk(16)][ks(16)][ln(64)][j(8)]  = V[l][e=colblk>>2][d=32ks+8(ln>>4)+j][r=16(colblk&3)+(ln&15)]
// Ub2[l][dblk(32)][ks(8)][ln][j]            = U[l][e=ks>>1][d=16dblk+(ln&15)][s=32(ks&1)+8(ln>>4)+j]
// Ct2[l][e(4)][oc(4)][kc(2)][ln][j]         = C[l][e][r=32kc+8(ln>>4)+j][s=16oc+(ln&15)]
__global__ void prep_kernel(const float* __restrict__ U, const float* __restrict__ V,
                            const float* __restrict__ C,
                            short* __restrict__ Vb2, short* __restrict__ Ub2,
                            short* __restrict__ Ct2)
{
    int tid  = blockIdx.x * 256 + threadIdx.x;
    int nthr = gridDim.x * 256;
    for (int i = tid; i < NL * 131072; i += nthr) {
        int l = i >> 17; int q = i & 131071;
        int colblk = q >> 13; int rem = q & 8191;
        int ks = rem >> 9; int ln = (rem >> 3) & 63; int j = rem & 7;
        int e = colblk >> 2;
        int r = (colblk & 3) * 16 + (ln & 15);
        int d = ks * 32 + (ln >> 4) * 8 + j;
        Vb2[i] = bf16rn(V[(((size_t)l * NE + e) * DD + d) * RR + r]);
    }
    for (int i = tid; i < NL * 131072; i += nthr) {
        int l = i >> 17; int q = i & 131071;
        int dblk = q >> 12; int rem = q & 4095;
        int ks = rem >> 9; int ln = (rem >> 3) & 63; int j = rem & 7;
        int e = ks >> 1;
        int d = dblk * 16 + (ln & 15);
        int s = (ks & 1) * 32 + (ln >> 4) * 8 + j;
        Ub2[i] = bf16rn(U[(((size_t)l * NE + e) * DD + d) * RR + s]);
    }
    for (int i = tid; i < NL * 16384; i += nthr) {
        int l = i >> 14; int q = i & 16383;
        int e = q >> 12; int rem = q & 4095;
        int oc = rem >> 10; int kc = (rem >> 9) & 1;
        int ln = (rem >> 3) & 63; int j = rem & 7;
        int r = kc * 32 + (ln >> 4) * 8 + j;
        int s = oc * 16 + (ln & 15);
        Ct2[i] = bf16rn(C[(((size_t)l * NE + e) * RR + r) * RR + s]);
    }
}

// XOR swizzle: breaks the bank conflict of row-major bf16 tiles on ds_read_b128
#define XLB_ADDR(row, colbyte) (((row) * (DD * 2)) + ((colbyte) ^ (((row) & 7) << 4)))
#define VB_ADDR(row, colbyte)  (((row) * (NE * RR * 2)) + ((colbyte) ^ (((row) & 7) << 4)))

__global__ __launch_bounds__(THREADS)
__attribute__((amdgpu_waves_per_eu(4, 4)))
void dcn_main(
    const float* __restrict__ x,
    const float* __restrict__ bias,
    const short* __restrict__ Vb2,
    const short* __restrict__ Ub2,
    const short* __restrict__ Ct2,
    float* __restrict__ out)
{
    __shared__ char xl_b[ROWS * DD * 2];        // 32 KiB bf16 xl tile (swizzled)
    __shared__ char vbuf[ROWS * NE * RR * 2];   // 16 KiB bf16 v tile (swizzled)
    __shared__ char cvbuf[ROWS * NE * RR * 2];  // 16 KiB bf16 cv tile (swizzled)

    const int t   = threadIdx.x;
    const int w   = t >> 6;          // wave 0..7
    const int ln  = t & 63;
    const int l15 = ln & 15;
    const int kg  = ln >> 4;         // k-group 0..3
    const int row_base = blockIdx.x * ROWS;

    // ---- preamble: single global read of x -> xlr (fp32), x0p (bf16x2), xl_b (bf16 LDS) ----
    float    xlr[2][4][4];   // fp32 xl state; wave owns d-cols [w*64, w*64+64), 2 M-tiles
    unsigned x0p[2][4][2];   // x0 packed bf16x2
    #pragma unroll
    for (int mt = 0; mt < 2; ++mt)
      #pragma unroll
      for (int nt = 0; nt < 4; ++nt) {
          int col  = w * 64 + nt * 16 + l15;
          int row0 = mt * 16 + kg * 4;
          const float* xp = x + (size_t)(row_base + row0) * DD + col;
          float v0 = xp[0], v1 = xp[DD], v2 = xp[2 * DD], v3 = xp[3 * DD];
          xlr[mt][nt][0] = v0; xlr[mt][nt][1] = v1; xlr[mt][nt][2] = v2; xlr[mt][nt][3] = v3;
          short b0 = bf16rn(v0), b1 = bf16rn(v1), b2 = bf16rn(v2), b3 = bf16rn(v3);
          x0p[mt][nt][0] = (unsigned)(unsigned short)b0 | ((unsigned)(unsigned short)b1 << 16);
          x0p[mt][nt][1] = (unsigned)(unsigned short)b2 | ((unsigned)(unsigned short)b3 << 16);
          *(short*)(xl_b + XLB_ADDR(row0 + 0, col * 2)) = b0;
          *(short*)(xl_b + XLB_ADDR(row0 + 1, col * 2)) = b1;
          *(short*)(xl_b + XLB_ADDR(row0 + 2, col * 2)) = b2;
          *(short*)(xl_b + XLB_ADDR(row0 + 3, col * 2)) = b3;
      }
    __syncthreads();

    const int e2 = w >> 1;           // GEMM2 expert for this wave
    const int h2 = w & 1;            // GEMM2 column-half within expert

    for (int layer = 0; layer < NL; ++layer) {
        const short* Vl = Vb2 + layer * 131072;
        const short* Ul = Ub2 + layer * 131072;
        const short* Cl = Ct2 + layer * 16384;
        const float* bl = bias + layer * DD;

        // bias for this wave's 4 cols (hoisted; latency hidden under GEMM1)
        float bias4[4];
        #pragma unroll
        for (int nt = 0; nt < 4; ++nt) bias4[nt] = 4.0f * bl[w * 64 + nt * 16 + l15];

        // ---- GEMM1: v = tanh(xl @ V); wave owns v-cols [w*32, w*32+32), nt 0..1 ----
        f32x4 acc1[2][2];
        #pragma unroll
        for (int mt = 0; mt < 2; ++mt)
          #pragma unroll
          for (int nt = 0; nt < 2; ++nt) { f32x4 z = {0.f, 0.f, 0.f, 0.f}; acc1[mt][nt] = z; }

        {
            bf16x8 bA[2], bB[2];
            #pragma unroll
            for (int nt = 0; nt < 2; ++nt)
                bA[nt] = *(const bf16x8*)(Vl + (((w * 2 + nt) * 16 + 0) << 9) + ln * 8);
            #pragma unroll
            for (int ks = 0; ks < 16; ++ks) {
                bf16x8* cur = (ks & 1) ? bB : bA;
                bf16x8* nxt = (ks & 1) ? bA : bB;
                if (ks < 15) {
                    #pragma unroll
                    for (int nt = 0; nt < 2; ++nt)
                        nxt[nt] = *(const bf16x8*)(Vl + (((w * 2 + nt) * 16 + ks + 1) << 9) + ln * 8);
                }
                const int d0 = ks * 32 + kg * 8;
                bf16x8 a0 = *(const bf16x8*)(xl_b + XLB_ADDR(l15,      d0 * 2));
                bf16x8 a1 = *(const bf16x8*)(xl_b + XLB_ADDR(l15 + 16, d0 * 2));
                acc1[0][0] = MFMA(a0, cur[0], acc1[0][0]);
                acc1[0][1] = MFMA(a0, cur[1], acc1[0][1]);
                acc1[1][0] = MFMA(a1, cur[0], acc1[1][0]);
                acc1[1][1] = MFMA(a1, cur[1], acc1[1][1]);
            }
        }
        #pragma unroll
        for (int mt = 0; mt < 2; ++mt)
          #pragma unroll
          for (int nt = 0; nt < 2; ++nt)
            #pragma unroll
            for (int r = 0; r < 4; ++r) {
                int row = mt * 16 + kg * 4 + r;
                int col = w * 32 + nt * 16 + l15;
                *(short*)(vbuf + VB_ADDR(row, col * 2)) = bf16rn(ftanh(acc1[mt][nt][r]));
            }
        __syncthreads();

        // ---- GEMM2: cv = tanh(v @ C_e); wave pair (2e,2e+1) owns expert e ----
        f32x4 acc2[2][2];
        #pragma unroll
        for (int mt = 0; mt < 2; ++mt)
          #pragma unroll
          for (int nt = 0; nt < 2; ++nt) { f32x4 z = {0.f, 0.f, 0.f, 0.f}; acc2[mt][nt] = z; }

        #pragma unroll
        for (int kc = 0; kc < 2; ++kc) {
            const int r0 = kc * 32 + kg * 8;
            const int vcol = e2 * 64 + r0;
            bf16x8 a0 = *(const bf16x8*)(vbuf + VB_ADDR(l15,      vcol * 2));
            bf16x8 a1 = *(const bf16x8*)(vbuf + VB_ADDR(l15 + 16, vcol * 2));
            #pragma unroll
            for (int nt = 0; nt < 2; ++nt) {
                bf16x8 b = *(const bf16x8*)(Cl + (((e2 * 4 + h2 * 2 + nt) * 2 + kc) << 9) + ln * 8);
                acc2[0][nt] = MFMA(a0, b, acc2[0][nt]);
                acc2[1][nt] = MFMA(a1, b, acc2[1][nt]);
            }
        }
        #pragma unroll
        for (int mt = 0; mt < 2; ++mt)
          #pragma unroll
          for (int nt = 0; nt < 2; ++nt)
            #pragma unroll
            for (int r = 0; r < 4; ++r) {
                int row = mt * 16 + kg * 4 + r;
                int col = e2 * 64 + h2 * 32 + nt * 16 + l15;
                *(short*)(cvbuf + VB_ADDR(row, col * 2)) = bf16rn(ftanh(acc2[mt][nt][r]));
            }
        __syncthreads();

        // ---- GEMM3 (two nt-halves): ucv = cv @ W; wave owns d-cols [w*64, +64) ----
        const bool lastL = (layer == NL - 1);
        #pragma unroll
        for (int half = 0; half < 2; ++half) {
            f32x4 acc3[2][2];
            #pragma unroll
            for (int mt = 0; mt < 2; ++mt)
              #pragma unroll
              for (int nt = 0; nt < 2; ++nt) { f32x4 z = {0.f, 0.f, 0.f, 0.f}; acc3[mt][nt] = z; }

            bf16x8 uA[2], uB[2];
            #pragma unroll
            for (int nt = 0; nt < 2; ++nt)
                uA[nt] = *(const bf16x8*)(Ul + (((w * 4 + half * 2 + nt) * 8 + 0) << 9) + ln * 8);
            #pragma unroll
            for (int ks = 0; ks < 8; ++ks) {
                bf16x8* cur = (ks & 1) ? uB : uA;
                bf16x8* nxt = (ks & 1) ? uA : uB;
                if (ks < 7) {
                    #pragma unroll
                    for (int nt = 0; nt < 2; ++nt)
                        nxt[nt] = *(const bf16x8*)(Ul + (((w * 4 + half * 2 + nt) * 8 + ks + 1) << 9) + ln * 8);
                }
                const int k0 = ks * 32 + kg * 8;
                bf16x8 a0 = *(const bf16x8*)(cvbuf + VB_ADDR(l15,      k0 * 2));
                bf16x8 a1 = *(const bf16x8*)(cvbuf + VB_ADDR(l15 + 16, k0 * 2));
                acc3[0][0] = MFMA(a0, cur[0], acc3[0][0]);
                acc3[0][1] = MFMA(a0, cur[1], acc3[0][1]);
                acc3[1][0] = MFMA(a1, cur[0], acc3[1][0]);
                acc3[1][1] = MFMA(a1, cur[1], acc3[1][1]);
            }

            // epilogue for this half: xl' = x0*(ucv + 4*bias) + xl
            #pragma unroll
            for (int nt = 0; nt < 2; ++nt) {
                const int ntg = half * 2 + nt;
                float bv = bias4[ntg];
                #pragma unroll
                for (int mt = 0; mt < 2; ++mt) {
                    unsigned p0 = x0p[mt][ntg][0], p1 = x0p[mt][ntg][1];
                    float x0v0 = __builtin_bit_cast(float, p0 << 16);
                    float x0v1 = __builtin_bit_cast(float, p0 & 0xffff0000u);
                    float x0v2 = __builtin_bit_cast(float, p1 << 16);
                    float x0v3 = __builtin_bit_cast(float, p1 & 0xffff0000u);
                    xlr[mt][ntg][0] = x0v0 * (acc3[mt][nt][0] + bv) + xlr[mt][ntg][0];
                    xlr[mt][ntg][1] = x0v1 * (acc3[mt][nt][1] + bv) + xlr[mt][ntg][1];
                    xlr[mt][ntg][2] = x0v2 * (acc3[mt][nt][2] + bv) + xlr[mt][ntg][2];
                    xlr[mt][ntg][3] = x0v3 * (acc3[mt][nt][3] + bv) + xlr[mt][ntg][3];
                }
            }
        }

        if (lastL) {
            #pragma unroll
            for (int mt = 0; mt < 2; ++mt)
              #pragma unroll
              for (int nt = 0; nt < 4; ++nt) {
                  int col = w * 64 + nt * 16 + l15;
                  float* op = out + (size_t)(row_base + mt * 16 + kg * 4) * DD + col;
                  op[0]      = xlr[mt][nt][0];
                  op[DD]     = xlr[mt][nt][1];
                  op[2 * DD] = xlr[mt][nt][2];
                  op[3 * DD] = xlr[mt][nt][3];
              }
        } else {
            // refresh bf16 xl tile for next layer's GEMM1 A-fragments
            #pragma unroll
            for (int mt = 0; mt < 2; ++mt)
              #pragma unroll
              for (int nt = 0; nt < 4; ++nt) {
                  int col = w * 64 + nt * 16 + l15;
                  #pragma unroll
                  for (int r = 0; r < 4; ++r) {
                      int row = mt * 16 + kg * 4 + r;
                      *(short*)(xl_b + XLB_ADDR(row, col * 2)) = bf16rn(xlr[mt][nt][r]);
                  }
              }
            __syncthreads();
        }
    }
}

extern "C" void kernel_launch(void* const* d_in, const int* in_sizes, int n_in,
                              void* d_out, int out_size, void* d_ws, size_t ws_size,
                              hipStream_t stream) {
    const float* x    = (const float*)d_in[0];
    const float* U    = (const float*)d_in[1];
    const float* V    = (const float*)d_in[2];
    const float* C    = (const float*)d_in[3];
    // d_in[4] = G : unused (gate == 1 exactly)
    const float* bias = (const float*)d_in[5];
    float* out = (float*)d_out;

    short* Vb2 = (short*)d_ws;                 // 786432 B
    short* Ub2 = Vb2 + NL * 131072;            // 786432 B
    short* Ct2 = Ub2 + NL * 131072;            // 98304 B  (total ~1.6 MiB)

    prep_kernel<<<dim3(256), dim3(256), 0, stream>>>(U, V, C, Vb2, Ub2, Ct2);
    dcn_main<<<dim3(16384 / ROWS), dim3(THREADS), 0, stream>>>(x, bias, Vb2, Ub2, Ct2, out);
}

// Round 7
// 101.435 us; speedup vs baseline: 1.8000x; 1.5560x over previous
//
#include <hip/hip_runtime.h>

// DCN-v2 low-rank mixture, L=3 E=4 D=512 R=64 B=16384.
// gate = softmax over size-1 axis == 1  -> G unused.
// xl' = x0 * (sum_e U_e tanh(C_e tanh(V_e^T xl)) + 4*bias) + xl, rows independent.
// R7: ZERO persistent per-thread register state (the R3-R6 spiller).
//     fp16 MFMA pipeline; xl carry lives as fp16 in LDS (same tile MFMA reads);
//     x0 re-read from global (L2) in layers 1-2, == xl_old in layer 0.
//     512 thr x ROWS=32, grid 512, LDS 64KB -> 2 blocks/CU, 16 waves/CU.

#define NL 3
#define NE 4
#define DD 512
#define RR 64
#define ROWS 32    // rows per block; grid = 16384/32 = 512 blocks
#define THREADS 512

typedef __attribute__((ext_vector_type(8))) _Float16 f16x8;   // 8 fp16 = 4 VGPR
typedef __attribute__((ext_vector_type(4))) float f32x4;

#define MFMA(a, b, c) __builtin_amdgcn_mfma_f32_16x16x32_f16((a), (b), (c), 0, 0, 0)

__device__ __forceinline__ short f16b(float f) {
    _Float16 h = (_Float16)f;
    return __builtin_bit_cast(short, h);
}
__device__ __forceinline__ float f16tof(short s) {
    return (float)__builtin_bit_cast(_Float16, s);
}

__device__ __forceinline__ float ftanh(float x) {
    float t = __builtin_amdgcn_exp2f(x * 2.8853900817779268f);
    return 1.0f - 2.0f * __builtin_amdgcn_rcpf(t + 1.0f);
}

// ---- prep: fp16-cast + permute weights into MFMA-fragment-contiguous order ----
// Fragment element (lane ln, j): col = 16*colblk + (ln&15), k = 32*kstep + (ln>>4)*8 + j.
// Vb2[l][colblk(16)][ks(16)][ln(64)][j(8)]  = V[l][e=colblk>>2][d=32ks+8(ln>>4)+j][r=16(colblk&3)+(ln&15)]
// Ub2[l][dblk(32)][ks(8)][ln][j]            = U[l][e=ks>>1][d=16dblk+(ln&15)][s=32(ks&1)+8(ln>>4)+j]
// Ct2[l][e(4)][oc(4)][kc(2)][ln][j]         = C[l][e][r=32kc+8(ln>>4)+j][s=16oc+(ln&15)]
__global__ void prep_kernel(const float* __restrict__ U, const float* __restrict__ V,
                            const float* __restrict__ C,
                            short* __restrict__ Vb2, short* __restrict__ Ub2,
                            short* __restrict__ Ct2)
{
    int tid  = blockIdx.x * 256 + threadIdx.x;
    int nthr = gridDim.x * 256;
    for (int i = tid; i < NL * 131072; i += nthr) {
        int l = i >> 17; int q = i & 131071;
        int colblk = q >> 13; int rem = q & 8191;
        int ks = rem >> 9; int ln = (rem >> 3) & 63; int j = rem & 7;
        int e = colblk >> 2;
        int r = (colblk & 3) * 16 + (ln & 15);
        int d = ks * 32 + (ln >> 4) * 8 + j;
        Vb2[i] = f16b(V[(((size_t)l * NE + e) * DD + d) * RR + r]);
    }
    for (int i = tid; i < NL * 131072; i += nthr) {
        int l = i >> 17; int q = i & 131071;
        int dblk = q >> 12; int rem = q & 4095;
        int ks = rem >> 9; int ln = (rem >> 3) & 63; int j = rem & 7;
        int e = ks >> 1;
        int d = dblk * 16 + (ln & 15);
        int s = (ks & 1) * 32 + (ln >> 4) * 8 + j;
        Ub2[i] = f16b(U[(((size_t)l * NE + e) * DD + d) * RR + s]);
    }
    for (int i = tid; i < NL * 16384; i += nthr) {
        int l = i >> 14; int q = i & 16383;
        int e = q >> 12; int rem = q & 4095;
        int oc = rem >> 10; int kc = (rem >> 9) & 1;
        int ln = (rem >> 3) & 63; int j = rem & 7;
        int r = kc * 32 + (ln >> 4) * 8 + j;
        int s = oc * 16 + (ln & 15);
        Ct2[i] = f16b(C[(((size_t)l * NE + e) * RR + r) * RR + s]);
    }
}

// XOR swizzle: breaks the 16-way bank conflict of row-major fp16 tiles on ds_read_b128
#define XLB_ADDR(row, colbyte) (((row) * (DD * 2)) + ((colbyte) ^ (((row) & 7) << 4)))
#define VB_ADDR(row, colbyte)  (((row) * (NE * RR * 2)) + ((colbyte) ^ (((row) & 7) << 4)))

__global__ __launch_bounds__(THREADS, 4) void dcn_main(
    const float* __restrict__ x,
    const float* __restrict__ bias,
    const short* __restrict__ Vb2,
    const short* __restrict__ Ub2,
    const short* __restrict__ Ct2,
    float* __restrict__ out)
{
    __shared__ char xl_b[ROWS * DD * 2];        // 32 KiB fp16 xl carry tile (swizzled)
    __shared__ char vbuf[ROWS * NE * RR * 2];   // 16 KiB fp16 v tile (swizzled)
    __shared__ char cvbuf[ROWS * NE * RR * 2];  // 16 KiB fp16 cv tile (swizzled)

    const int t   = threadIdx.x;
    const int w   = t >> 6;          // wave 0..7
    const int ln  = t & 63;
    const int l15 = ln & 15;
    const int kg  = ln >> 4;         // k-group 0..3
    const int row_base = blockIdx.x * ROWS;

    // ---- preamble: x (fp32) -> fp16 LDS tile; no per-thread state kept ----
    #pragma unroll
    for (int q = 0; q < 8; ++q) {
        int p   = t + q * THREADS;
        int row = p >> 7;                 // 128 float4 per row
        int d4  = (p & 127) << 2;
        const float4 v4 = *(const float4*)(x + (size_t)(row_base + row) * DD + d4);
        short4 pk;
        pk.x = f16b(v4.x); pk.y = f16b(v4.y); pk.z = f16b(v4.z); pk.w = f16b(v4.w);
        *(short4*)(xl_b + XLB_ADDR(row, d4 * 2)) = pk;
    }
    __syncthreads();

    const int e2 = w >> 1;           // GEMM2 expert for this wave
    const int h2 = w & 1;            // GEMM2 column-half within expert

    #pragma unroll
    for (int layer = 0; layer < NL; ++layer) {
        const short* Vl = Vb2 + layer * 131072;
        const short* Ul = Ub2 + layer * 131072;
        const short* Cl = Ct2 + layer * 16384;
        const float* bl = bias + layer * DD;

        // ---- GEMM1: v = tanh(xl @ V); wave owns v-cols [w*32, w*32+32) ----
        f32x4 acc1[2][2];
        #pragma unroll
        for (int mt = 0; mt < 2; ++mt)
          #pragma unroll
          for (int nt = 0; nt < 2; ++nt) { f32x4 z = {0.f, 0.f, 0.f, 0.f}; acc1[mt][nt] = z; }

        #pragma unroll 4
        for (int ks = 0; ks < 16; ++ks) {
            const int d0 = ks * 32 + kg * 8;
            f16x8 a0 = *(const f16x8*)(xl_b + XLB_ADDR(l15,      d0 * 2));
            f16x8 a1 = *(const f16x8*)(xl_b + XLB_ADDR(l15 + 16, d0 * 2));
            #pragma unroll
            for (int nt = 0; nt < 2; ++nt) {
                f16x8 b = *(const f16x8*)(Vl + (((w * 2 + nt) * 16 + ks) << 9) + ln * 8);
                acc1[0][nt] = MFMA(a0, b, acc1[0][nt]);
                acc1[1][nt] = MFMA(a1, b, acc1[1][nt]);
            }
        }
        #pragma unroll
        for (int mt = 0; mt < 2; ++mt)
          #pragma unroll
          for (int nt = 0; nt < 2; ++nt)
            #pragma unroll
            for (int r = 0; r < 4; ++r) {
                int row = mt * 16 + kg * 4 + r;
                int col = w * 32 + nt * 16 + l15;
                *(short*)(vbuf + VB_ADDR(row, col * 2)) = f16b(ftanh(acc1[mt][nt][r]));
            }
        __syncthreads();

        // ---- GEMM2: cv = tanh(v @ C_e); wave pair (2e,2e+1) owns expert e ----
        f32x4 acc2[2][2];
        #pragma unroll
        for (int mt = 0; mt < 2; ++mt)
          #pragma unroll
          for (int nt = 0; nt < 2; ++nt) { f32x4 z = {0.f, 0.f, 0.f, 0.f}; acc2[mt][nt] = z; }

        #pragma unroll
        for (int kc = 0; kc < 2; ++kc) {
            const int r0 = kc * 32 + kg * 8;
            const int vcol = e2 * 64 + r0;
            f16x8 a0 = *(const f16x8*)(vbuf + VB_ADDR(l15,      vcol * 2));
            f16x8 a1 = *(const f16x8*)(vbuf + VB_ADDR(l15 + 16, vcol * 2));
            #pragma unroll
            for (int nt = 0; nt < 2; ++nt) {
                f16x8 b = *(const f16x8*)(Cl + (((e2 * 4 + h2 * 2 + nt) * 2 + kc) << 9) + ln * 8);
                acc2[0][nt] = MFMA(a0, b, acc2[0][nt]);
                acc2[1][nt] = MFMA(a1, b, acc2[1][nt]);
            }
        }
        #pragma unroll
        for (int mt = 0; mt < 2; ++mt)
          #pragma unroll
          for (int nt = 0; nt < 2; ++nt)
            #pragma unroll
            for (int r = 0; r < 4; ++r) {
                int row = mt * 16 + kg * 4 + r;
                int col = e2 * 64 + h2 * 32 + nt * 16 + l15;
                *(short*)(cvbuf + VB_ADDR(row, col * 2)) = f16b(ftanh(acc2[mt][nt][r]));
            }
        __syncthreads();

        // ---- GEMM3: ucv = cv @ W, W[(e,s)][d] = U[e][d][s]; wave owns d-cols [w*64, +64) ----
        f32x4 acc3[2][4];
        #pragma unroll
        for (int mt = 0; mt < 2; ++mt)
          #pragma unroll
          for (int nt = 0; nt < 4; ++nt) { f32x4 z = {0.f, 0.f, 0.f, 0.f}; acc3[mt][nt] = z; }

        #pragma unroll 2
        for (int ks = 0; ks < 8; ++ks) {
            const int k0 = ks * 32 + kg * 8;
            f16x8 a0 = *(const f16x8*)(cvbuf + VB_ADDR(l15,      k0 * 2));
            f16x8 a1 = *(const f16x8*)(cvbuf + VB_ADDR(l15 + 16, k0 * 2));
            #pragma unroll
            for (int nt = 0; nt < 4; ++nt) {
                f16x8 b = *(const f16x8*)(Ul + (((w * 4 + nt) * 8 + ks) << 9) + ln * 8);
                acc3[0][nt] = MFMA(a0, b, acc3[0][nt]);
                acc3[1][nt] = MFMA(a1, b, acc3[1][nt]);
            }
        }

        // ---- epilogue: xl' = x0*(ucv + 4*bias) + xl_old; carry stays in LDS fp16 ----
        // layer 0: x0 == xl_old (LDS). layers 1,2: x0 re-read from global x (L2-resident).
        const bool lastL = (layer == NL - 1);
        #pragma unroll
        for (int nt = 0; nt < 4; ++nt) {
            const int col = w * 64 + nt * 16 + l15;
            const float bv = 4.0f * bl[col];
            #pragma unroll
            for (int mt = 0; mt < 2; ++mt) {
                const int row0 = mt * 16 + kg * 4;
                // xl_old from LDS fp16
                float xo0 = f16tof(*(const short*)(xl_b + XLB_ADDR(row0 + 0, col * 2)));
                float xo1 = f16tof(*(const short*)(xl_b + XLB_ADDR(row0 + 1, col * 2)));
                float xo2 = f16tof(*(const short*)(xl_b + XLB_ADDR(row0 + 2, col * 2)));
                float xo3 = f16tof(*(const short*)(xl_b + XLB_ADDR(row0 + 3, col * 2)));
                float x00, x01, x02, x03;
                if (layer == 0) {
                    x00 = xo0; x01 = xo1; x02 = xo2; x03 = xo3;
                } else {
                    const float* xp = x + (size_t)(row_base + row0) * DD + col;
                    x00 = xp[0]; x01 = xp[DD]; x02 = xp[2 * DD]; x03 = xp[3 * DD];
                }
                float n0 = x00 * (acc3[mt][nt][0] + bv) + xo0;
                float n1 = x01 * (acc3[mt][nt][1] + bv) + xo1;
                float n2 = x02 * (acc3[mt][nt][2] + bv) + xo2;
                float n3 = x03 * (acc3[mt][nt][3] + bv) + xo3;
                if (lastL) {
                    float* op = out + (size_t)(row_base + row0) * DD + col;
                    op[0] = n0; op[DD] = n1; op[2 * DD] = n2; op[3 * DD] = n3;
                } else {
                    *(short*)(xl_b + XLB_ADDR(row0 + 0, col * 2)) = f16b(n0);
                    *(short*)(xl_b + XLB_ADDR(row0 + 1, col * 2)) = f16b(n1);
                    *(short*)(xl_b + XLB_ADDR(row0 + 2, col * 2)) = f16b(n2);
                    *(short*)(xl_b + XLB_ADDR(row0 + 3, col * 2)) = f16b(n3);
                }
            }
        }
        if (!lastL) __syncthreads();   // next GEMM1 reads all xl cols
    }
}

extern "C" void kernel_launch(void* const* d_in, const int* in_sizes, int n_in,
                              void* d_out, int out_size, void* d_ws, size_t ws_size,
                              hipStream_t stream) {
    const float* x    = (const float*)d_in[0];
    const float* U    = (const float*)d_in[1];
    const float* V    = (const float*)d_in[2];
    const float* C    = (const float*)d_in[3];
    // d_in[4] = G : unused (gate == 1 exactly)
    const float* bias = (const float*)d_in[5];
    float* out = (float*)d_out;

    short* Vb2 = (short*)d_ws;                 // 786432 B
    short* Ub2 = Vb2 + NL * 131072;            // 786432 B
    short* Ct2 = Ub2 + NL * 131072;            // 98304 B  (total ~1.6 MiB)

    prep_kernel<<<dim3(256), dim3(256), 0, stream>>>(U, V, C, Vb2, Ub2, Ct2);
    dcn_main<<<dim3(16384 / ROWS), dim3(THREADS), 0, stream>>>(x, bias, Vb2, Ub2, Ct2, out);
}